// Round 3
// baseline (197.444 us; speedup 1.0000x reference)
//
#include <hip/hip_runtime.h>
#include <math.h>

#define DD 64
#define CC 128
#define HH 512
#define BATCH 4096

typedef __attribute__((ext_vector_type(2))) float f32x2;
typedef unsigned long long u64;

__device__ __forceinline__ f32x2 splat2(float x) { f32x2 v; v[0] = x; v[1] = x; return v; }

// packed FMA, all-VGPR form: d = a*b + c on both halves
__device__ __forceinline__ f32x2 pk_fma(f32x2 a, f32x2 b, f32x2 c) {
    f32x2 d;
    asm("v_pk_fma_f32 %0, %1, %2, %3" : "=v"(d) : "v"(a), "v"(b), "v"(c));
    return d;
}
// packed FMA with the one legal scalar source: src0 is an SGPR pair {h,h}.
// Saves the 2 v_mov splat per broadcast scalar (marshaling moves to SALU).
__device__ __forceinline__ f32x2 pk_fma_s(u64 hpair, f32x2 b, f32x2 c) {
    f32x2 d;
    asm("v_pk_fma_f32 %0, %1, %2, %3" : "=v"(d) : "s"(hpair), "v"(b), "v"(c));
    return d;
}

__device__ __forceinline__ float fast_softplus(float x) {
    float t = exp2f(-fabsf(x) * 1.44269504f);
    return fmaxf(x, 0.f) + 0.69314718f * log2f(1.f + t);
}

// wave-uniform broadcast via v_readlane (SGPR result)
__device__ __forceinline__ float bcast(float x, int l) {
    return __int_as_float(__builtin_amdgcn_readlane(__float_as_int(x), l));
}
// broadcast to an SGPR pair {x,x} for pk_fma_s (build is SALU, co-issues)
__device__ __forceinline__ u64 rl_pair(float x, int l) {
    unsigned u = (unsigned)__builtin_amdgcn_readlane(__float_as_int(x), l);
    return ((u64)u << 32) | u;
}

typedef const __attribute__((address_space(1))) void* as1_cptr;
typedef __attribute__((address_space(3))) void* as3_ptr;
__device__ __forceinline__ void glds16(const float* g, float* l) {
    __builtin_amdgcn_global_load_lds((as1_cptr)g, (as3_ptr)l, 16, 0, 0);
}

// One block = 8 waves x R=2 rows = 16 batch rows; grid 256 -> 1 block/CU
// (still 2 waves/SIMD). vs round 2:
//  - merged block: weights staged ONCE per CU (was twice) -> half the
//    L2->LDS traffic and half the per-wave staging instructions;
//  - hoisted ds-read cluster pinned with sched_barrier(0) (round-2 counters
//    showed the compiler re-sank the hoist: VGPR stayed at 92);
//  - readlane broadcasts feed v_pk_fma_f32 as SGPR-pair scalar source
//    (pk_fma_s) -> v_mov splats deleted from the VALU stream.
__global__ __launch_bounds__(512, 2) void made_sample(
    const float* __restrict__ ctx,   // (B, C)
    const float* __restrict__ eps,   // (B, D)
    const float* __restrict__ W1,    // (D+C, H)
    const float* __restrict__ b1,    // (H)
    const float* __restrict__ W2,    // (H, H)
    const float* __restrict__ b2,    // (H)
    const float* __restrict__ W3,    // (H, 2D)
    const float* __restrict__ b3,    // (2D)
    float* __restrict__ out)         // (B, D)
{
    const int lane  = threadIdx.x & 63;
    const int w     = threadIdx.x >> 6;          // wave 0..7
    const int rbase = blockIdx.x * 16 + w * 2;   // 2 batch rows per wave
    const int jbase = 8 * lane;

    __shared__ float sbuf[2][10 * HH];           // 2 x 20 KB (slots: 9 W2 + 1 W1)
    __shared__ float w3sb[2][5 * 256];           // 2 x 5 KB  (5 pairs of W3 rows)

    int deg[8];
    #pragma unroll
    for (int u = 0; u < 8; ++u) deg[u] = (jbase + u) % 63 + 1;

    // split-half LDS read: slot base -> 4 f32x2 (8 floats) for this lane
    auto load8v = [&](const float* base_, f32x2* r_) {
        float4 a = *(const float4*)(base_ + lane * 4);
        float4 b = *(const float4*)(base_ + 256 + lane * 4);
        r_[0][0] = a.x; r_[0][1] = a.y; r_[1][0] = a.z; r_[1][1] = a.w;
        r_[2][0] = b.x; r_[2][1] = b.y; r_[3][0] = b.z; r_[3][1] = b.w;
    };
    auto stage_row = [&](const float* src, float* dst) {
        glds16(src + lane * 8,     dst);
        glds16(src + lane * 8 + 4, dst + 256);
    };
    // stage W3 rows k0,k1 (128 floats each) into one 1KB pair slot:
    // lanes 0..31 carry row k0 (bytes 0..511), lanes 32..63 row k1 (512..1023).
    auto stage_w3pair = [&](int k0, int k1, float* dst) {
        const float* g = (lane < 32) ? (W3 + k0 * (2 * DD) + lane * 4)
                                     : (W3 + k1 * (2 * DD) + (lane - 32) * 4);
        glds16(g, dst);
    };

    f32x2 p1[2][4], p2[2][4], acc[2];
    #pragma unroll
    for (int j = 0; j < 4; ++j) {
        f32x2 t1, t2;
        t1[0] = b1[jbase + 2 * j]; t1[1] = b1[jbase + 2 * j + 1];
        t2[0] = b2[jbase + 2 * j]; t2[1] = b2[jbase + 2 * j + 1];
        p1[0][j] = t1; p1[1][j] = t1;
        p2[0][j] = t2; p2[1][j] = t2;
    }
    acc[0] = splat2(0.f);
    acc[1] = splat2(0.f);

    float ca[2], cb[2], ep[2];
    #pragma unroll
    for (int r = 0; r < 2; ++r) {
        ca[r] = ctx[(rbase + r) * CC + lane];
        cb[r] = ctx[(rbase + r) * CC + 64 + lane];
        ep[r] = eps[(rbase + r) * DD + lane];
    }
    const float b3m = b3[lane];        // bias for mean col `lane`
    const float b3p = b3[64 + lane];   // bias for prescale col `lane`

    // ctx chunk ch: W1 rows DD+8ch..DD+8ch+7 -> slots 0..7 (1 row per wave)
    auto stage_ctx = [&](int ch, float* buf) {
        stage_row(W1 + (DD + 8 * ch + w) * HH, buf + w * HH);
    };
    // staging for main step `in`, spread over 8 waves:
    //   wave w (0..7): W2 row basen+63*w -> slot w
    //   wave 0: + W2 row basen+504 -> slot 8      (iff basen<8)
    //   wave 1: + W1 row `in` -> slot 9
    //   waves 2..5: W3 pair p=w-2 (rows basen+63*2p, basen+63*(2p+1))
    //   wave 6: W3 pair 4 (row basen+504 dup)     (iff basen<8)
    auto stage_step = [&](int in, float* buf, float* w3buf) {
        if (in == 0) {                       // step 0 needs only W1 row 0
            if (w == 1) stage_row(W1, buf + 9 * HH);
            return;
        }
        const int basen = in - 1;
        const bool h9n = basen < 8;
        stage_row(W2 + (basen + 63 * w) * HH, buf + w * HH);
        if (w == 0 && h9n) stage_row(W2 + (basen + 504) * HH, buf + 8 * HH);
        if (w == 1) stage_row(W1 + in * HH, buf + 9 * HH);
        if (w >= 2 && w <= 5) {
            const int p = w - 2;
            stage_w3pair(basen + 63 * (2 * p), basen + 63 * (2 * p + 1),
                         w3buf + p * 256);
        }
        if (w == 6 && h9n)
            stage_w3pair(basen + 504, basen + 504, w3buf + 4 * 256);
    };

    // ---- context init: pre1 += ctx @ W1[D:,:], 16 chunks of 8 rows ----
    stage_ctx(0, sbuf[0]);
    __syncthreads();
    #pragma unroll 1
    for (int ch = 0; ch < 16; ++ch) {
        float* cur = sbuf[ch & 1];
        if (ch < 15) stage_ctx(ch + 1, sbuf[(ch + 1) & 1]);
        else         stage_step(0, sbuf[0], w3sb[0]);   // (16)&1==0: parity OK
        // hoisted weight reads, pinned above the compute
        f32x2 cw[8][4];
        #pragma unroll
        for (int q = 0; q < 8; ++q) load8v(cur + q * HH, cw[q]);
        __builtin_amdgcn_sched_barrier(0);
        #pragma unroll
        for (int q = 0; q < 8; ++q) {
            const int c = 8 * ch + q;
            #pragma unroll
            for (int r = 0; r < 2; ++r) {
                const u64 cvp = rl_pair((ch < 8) ? ca[r] : cb[r], c & 63);
                #pragma unroll
                for (int j = 0; j < 4; ++j) p1[r][j] = pk_fma_s(cvp, cw[q][j], p1[r][j]);
            }
        }
        __syncthreads();
    }

    float z[2] = {0.f, 0.f};

    // ---- autoregressive main loop ----
    #pragma unroll 1
    for (int i = 0; i < DD; ++i) {
        float* cur = sbuf[i & 1];
        const float* w3s = w3sb[i & 1];

        // issue next-step staging first (vmcnt countdown starts earliest)
        if (i < 63) stage_step(i + 1, sbuf[(i + 1) & 1], w3sb[(i + 1) & 1]);

        // ---- hoisted LDS reads: everything this iteration needs ----
        f32x2 w1v[4];
        load8v(cur + 9 * HH, w1v);
        f32x2 wv[9][4];
        float wa[9], wb[9];
        if (i > 0) {
            #pragma unroll
            for (int t = 0; t < 9; ++t) load8v(cur + t * HH, wv[t]);
            #pragma unroll
            for (int t = 0; t < 9; ++t) {
                wa[t] = w3s[t * 128 + lane];        // W3[k_t, lane]
                wb[t] = w3s[t * 128 + 64 + lane];   // W3[k_t, 64+lane]
            }
        }
        __builtin_amdgcn_sched_barrier(0);   // pin loads above the compute

        if (i > 0) {                      // i==0: no unit has deg==0, all h==0
            const int base = i - 1;
            const bool h9 = base < 8;     // 9th finalizing unit exists (i<=8)

            // (a) select finalized h1 (deg==i); compares shared with (c)
            float m0 = 0.f, m1 = 0.f;
            #pragma unroll
            for (int u = 0; u < 8; ++u) {
                const bool e = (deg[u] == i);
                m0 = e ? p1[0][u >> 1][u & 1] : m0;
                m1 = e ? p1[1][u >> 1][u & 1] : m1;
            }
            m0 = fmaxf(m0, 0.f);
            m1 = fmaxf(m1, 0.f);

            // (b) rank update of pre2 (packed FMA, SGPR-pair h operand)
            #pragma unroll
            for (int t = 0; t < 8; ++t) {
                const int k = base + 63 * t;
                const u64 h0 = rl_pair(m0, k >> 3);
                const u64 h1 = rl_pair(m1, k >> 3);
                #pragma unroll
                for (int j = 0; j < 4; ++j) {
                    p2[0][j] = pk_fma_s(h0, wv[t][j], p2[0][j]);
                    p2[1][j] = pk_fma_s(h1, wv[t][j], p2[1][j]);
                }
            }
            if (h9) {                     // t=8: unit base+504, owner lane 63
                const u64 h0 = rl_pair(m0, 63);
                const u64 h1 = rl_pair(m1, 63);
                #pragma unroll
                for (int j = 0; j < 4; ++j) {
                    p2[0][j] = pk_fma_s(h0, wv[8][j], p2[0][j]);
                    p2[1][j] = pk_fma_s(h1, wv[8][j], p2[1][j]);
                }
            }

            // (c) capture newly-final h2 (deg==i)
            float g0 = 0.f, g1 = 0.f;
            #pragma unroll
            for (int u = 0; u < 8; ++u) {
                const bool e = (deg[u] == i);
                g0 = e ? p2[0][u >> 1][u & 1] : g0;
                g1 = e ? p2[1][u >> 1][u & 1] : g1;
            }
            g0 = fmaxf(g0, 0.f);
            g1 = fmaxf(g1, 0.f);

            // (d) incremental W3 accumulation (scalar v_fmac, SGPR h operand)
            #pragma unroll
            for (int t = 0; t < 8; ++t) {
                const int k = base + 63 * t;
                const float h0 = bcast(g0, k >> 3);
                const float h1 = bcast(g1, k >> 3);
                acc[0][0] = fmaf(h0, wa[t], acc[0][0]);
                acc[0][1] = fmaf(h0, wb[t], acc[0][1]);
                acc[1][0] = fmaf(h1, wa[t], acc[1][0]);
                acc[1][1] = fmaf(h1, wb[t], acc[1][1]);
            }
            if (h9) {
                const float h0 = bcast(g0, 63);
                const float h1 = bcast(g1, 63);
                acc[0][0] = fmaf(h0, wa[8], acc[0][0]);
                acc[0][1] = fmaf(h0, wb[8], acc[0][1]);
                acc[1][0] = fmaf(h1, wa[8], acc[1][0]);
                acc[1][1] = fmaf(h1, wb[8], acc[1][1]);
            }
        }

        // (e) z_i: column i's totals live in lane i; every lane computes its
        // own candidate (parallel), one readlane extracts; feed back into p1.
        {
            #pragma unroll
            for (int r = 0; r < 2; ++r) {
                const float am = acc[r][0] + b3m;
                const float ap = acc[r][1] + b3p;
                const float sp = fast_softplus(ap);
                const float zc = fmaf(sp, ep[r], am);
                const float zi = bcast(zc, i);
                if (lane == i) z[r] = zi;
                const u64 zp = rl_pair(zc, i);
                #pragma unroll
                for (int j = 0; j < 4; ++j) p1[r][j] = pk_fma_s(zp, w1v[j], p1[r][j]);
            }
        }

        __syncthreads();
    }

    #pragma unroll
    for (int r = 0; r < 2; ++r) out[(rbase + r) * DD + lane] = z[r];
}

extern "C" void kernel_launch(void* const* d_in, const int* in_sizes, int n_in,
                              void* d_out, int out_size, void* d_ws, size_t ws_size,
                              hipStream_t stream) {
    const float* ctx = (const float*)d_in[0];
    const float* eps = (const float*)d_in[1];
    const float* W1  = (const float*)d_in[2];
    const float* b1  = (const float*)d_in[3];
    const float* W2  = (const float*)d_in[4];
    const float* b2  = (const float*)d_in[5];
    const float* W3  = (const float*)d_in[6];
    const float* b3  = (const float*)d_in[7];
    (void)d_ws; (void)ws_size; (void)in_sizes; (void)n_in; (void)out_size;

    made_sample<<<BATCH / 16, 512, 0, stream>>>(ctx, eps, W1, b1, W2, b2, W3, b3,
                                                (float*)d_out);
}

// Round 4
// 175.490 us; speedup vs baseline: 1.1251x; 1.1251x over previous
//
#include <hip/hip_runtime.h>
#include <math.h>

#define DD 64
#define CC 128
#define HH 512
#define BATCH 4096

typedef __attribute__((ext_vector_type(2))) float f32x2;
typedef unsigned long long u64;

__device__ __forceinline__ f32x2 splat2(float x) { f32x2 v; v[0] = x; v[1] = x; return v; }

// packed FMA with the one legal scalar source: src0 is an SGPR pair {h,h}.
// Saves the 2 v_mov splat per broadcast scalar (marshaling moves to SALU).
__device__ __forceinline__ f32x2 pk_fma_s(u64 hpair, f32x2 b, f32x2 c) {
    f32x2 d;
    asm("v_pk_fma_f32 %0, %1, %2, %3" : "=v"(d) : "s"(hpair), "v"(b), "v"(c));
    return d;
}

__device__ __forceinline__ float fast_softplus(float x) {
    float t = exp2f(-fabsf(x) * 1.44269504f);
    return fmaxf(x, 0.f) + 0.69314718f * log2f(1.f + t);
}

// wave-uniform broadcast via v_readlane (SGPR result)
__device__ __forceinline__ float bcast(float x, int l) {
    return __int_as_float(__builtin_amdgcn_readlane(__float_as_int(x), l));
}
// broadcast to an SGPR pair {x,x} for pk_fma_s (build is SALU, co-issues)
__device__ __forceinline__ u64 rl_pair(float x, int l) {
    unsigned u = (unsigned)__builtin_amdgcn_readlane(__float_as_int(x), l);
    return ((u64)u << 32) | u;
}

typedef const __attribute__((address_space(1))) void* as1_cptr;
typedef __attribute__((address_space(3))) void* as3_ptr;
__device__ __forceinline__ void glds16(const float* g, float* l) {
    __builtin_amdgcn_global_load_lds((as1_cptr)g, (as3_ptr)l, 16, 0, 0);
}

// One block = 8 waves x R=1 row = 8 batch rows; grid 512 -> 2 blocks/CU,
// 16 waves/CU = 4 waves/SIMD (2x round-2 TLP).
//
// Geometry rationale (R2/R3 counters): R2 (2 blocks/CU, 2 waves/SIMD) floor
// was both-waves-stalled barrier drains (VALUBusy 58%, dur 128us). R3's merged
// single block/CU removed cross-block overlap -> dur 151us, VALUBusy 42%,
// BUT its 8-wave staging split + SALU-pair broadcasts cut per-SIMD VALU time
// 15%. This round keeps the 8-wave block (same 50KB/CU/iter L2->LDS traffic
// as R2, staged once per block) and halves per-wave rows so TWO such blocks
// fit per CU: cross-block drain overlap restored, twice the waves/SIMD to
// cover LDS/L2 latency, per-wave FMA work halved.
__global__ __launch_bounds__(512, 4) void made_sample(
    const float* __restrict__ ctx,   // (B, C)
    const float* __restrict__ eps,   // (B, D)
    const float* __restrict__ W1,    // (D+C, H)
    const float* __restrict__ b1,    // (H)
    const float* __restrict__ W2,    // (H, H)
    const float* __restrict__ b2,    // (H)
    const float* __restrict__ W3,    // (H, 2D)
    const float* __restrict__ b3,    // (2D)
    float* __restrict__ out)         // (B, D)
{
    const int lane  = threadIdx.x & 63;
    const int w     = threadIdx.x >> 6;          // wave 0..7
    const int rrow  = blockIdx.x * 8 + w;        // 1 batch row per wave
    const int jbase = 8 * lane;

    __shared__ float sbuf[2][10 * HH];           // 2 x 20 KB (slots: 9 W2 + 1 W1)
    __shared__ float w3sb[2][5 * 256];           // 2 x 5 KB  (5 pairs of W3 rows)

    int deg[8];
    #pragma unroll
    for (int u = 0; u < 8; ++u) deg[u] = (jbase + u) % 63 + 1;

    // split-half LDS read: slot base -> 4 f32x2 (8 floats) for this lane
    auto load8v = [&](const float* base_, f32x2* r_) {
        float4 a = *(const float4*)(base_ + lane * 4);
        float4 b = *(const float4*)(base_ + 256 + lane * 4);
        r_[0][0] = a.x; r_[0][1] = a.y; r_[1][0] = a.z; r_[1][1] = a.w;
        r_[2][0] = b.x; r_[2][1] = b.y; r_[3][0] = b.z; r_[3][1] = b.w;
    };
    auto stage_row = [&](const float* src, float* dst) {
        glds16(src + lane * 8,     dst);
        glds16(src + lane * 8 + 4, dst + 256);
    };
    // stage W3 rows k0,k1 (128 floats each) into one 1KB pair slot:
    // lanes 0..31 carry row k0 (bytes 0..511), lanes 32..63 row k1 (512..1023).
    auto stage_w3pair = [&](int k0, int k1, float* dst) {
        const float* g = (lane < 32) ? (W3 + k0 * (2 * DD) + lane * 4)
                                     : (W3 + k1 * (2 * DD) + (lane - 32) * 4);
        glds16(g, dst);
    };

    f32x2 p1[4], p2[4], acc;
    #pragma unroll
    for (int j = 0; j < 4; ++j) {
        p1[j][0] = b1[jbase + 2 * j]; p1[j][1] = b1[jbase + 2 * j + 1];
        p2[j][0] = b2[jbase + 2 * j]; p2[j][1] = b2[jbase + 2 * j + 1];
    }
    acc = splat2(0.f);

    const float ca = ctx[rrow * CC + lane];
    const float cb = ctx[rrow * CC + 64 + lane];
    const float ep = eps[rrow * DD + lane];
    const float b3m = b3[lane];        // bias for mean col `lane`
    const float b3p = b3[64 + lane];   // bias for prescale col `lane`

    // ctx chunk ch: W1 rows DD+8ch..DD+8ch+7 -> slots 0..7 (1 row per wave)
    auto stage_ctx = [&](int ch, float* buf) {
        stage_row(W1 + (DD + 8 * ch + w) * HH, buf + w * HH);
    };
    // staging for main step `in`, spread over 8 waves:
    //   wave w (0..7): W2 row basen+63*w -> slot w
    //   wave 0: + W2 row basen+504 -> slot 8      (iff basen<8)
    //   wave 1: + W1 row `in` -> slot 9
    //   waves 2..5: W3 pair p=w-2 (rows basen+63*2p, basen+63*(2p+1))
    //   wave 6: W3 pair 4 (row basen+504 dup)     (iff basen<8)
    auto stage_step = [&](int in, float* buf, float* w3buf) {
        if (in == 0) {                       // step 0 needs only W1 row 0
            if (w == 1) stage_row(W1, buf + 9 * HH);
            return;
        }
        const int basen = in - 1;
        const bool h9n = basen < 8;
        stage_row(W2 + (basen + 63 * w) * HH, buf + w * HH);
        if (w == 0 && h9n) stage_row(W2 + (basen + 504) * HH, buf + 8 * HH);
        if (w == 1) stage_row(W1 + in * HH, buf + 9 * HH);
        if (w >= 2 && w <= 5) {
            const int p = w - 2;
            stage_w3pair(basen + 63 * (2 * p), basen + 63 * (2 * p + 1),
                         w3buf + p * 256);
        }
        if (w == 6 && h9n)
            stage_w3pair(basen + 504, basen + 504, w3buf + 4 * 256);
    };

    // ---- context init: pre1 += ctx @ W1[D:,:], 16 chunks of 8 rows ----
    stage_ctx(0, sbuf[0]);
    __syncthreads();
    #pragma unroll 1
    for (int ch = 0; ch < 16; ++ch) {
        float* cur = sbuf[ch & 1];
        if (ch < 15) stage_ctx(ch + 1, sbuf[(ch + 1) & 1]);
        else         stage_step(0, sbuf[0], w3sb[0]);   // (16)&1==0: parity OK
        #pragma unroll
        for (int q = 0; q < 8; ++q) {
            f32x2 cw[4];
            load8v(cur + q * HH, cw);
            const int c = 8 * ch + q;
            const u64 cvp = rl_pair((ch < 8) ? ca : cb, c & 63);
            #pragma unroll
            for (int j = 0; j < 4; ++j) p1[j] = pk_fma_s(cvp, cw[j], p1[j]);
        }
        __syncthreads();
    }

    float z = 0.f;

    // ---- autoregressive main loop ----
    #pragma unroll 1
    for (int i = 0; i < DD; ++i) {
        float* cur = sbuf[i & 1];
        const float* w3s = w3sb[i & 1];

        // issue next-step staging first (vmcnt countdown starts earliest)
        if (i < 63) stage_step(i + 1, sbuf[(i + 1) & 1], w3sb[(i + 1) & 1]);

        f32x2 w1v[4];
        load8v(cur + 9 * HH, w1v);

        if (i > 0) {                      // i==0: no unit has deg==0, all h==0
            const int base = i - 1;
            const bool h9 = base < 8;     // 9th finalizing unit exists (i<=8)

            // (a) select finalized h1 (deg==i); compares shared with (c)
            float m0 = 0.f;
            #pragma unroll
            for (int u = 0; u < 8; ++u)
                m0 = (deg[u] == i) ? p1[u >> 1][u & 1] : m0;
            m0 = fmaxf(m0, 0.f);

            // (b) rank update of pre2 (packed FMA, SGPR-pair h operand)
            #pragma unroll
            for (int t = 0; t < 8; ++t) {
                const int k = base + 63 * t;
                f32x2 wv[4];
                load8v(cur + t * HH, wv);
                const u64 h0 = rl_pair(m0, k >> 3);
                #pragma unroll
                for (int j = 0; j < 4; ++j) p2[j] = pk_fma_s(h0, wv[j], p2[j]);
            }
            if (h9) {                     // t=8: unit base+504, owner lane 63
                f32x2 wv[4];
                load8v(cur + 8 * HH, wv);
                const u64 h0 = rl_pair(m0, 63);
                #pragma unroll
                for (int j = 0; j < 4; ++j) p2[j] = pk_fma_s(h0, wv[j], p2[j]);
            }

            // (c) capture newly-final h2 (deg==i)
            float g0 = 0.f;
            #pragma unroll
            for (int u = 0; u < 8; ++u)
                g0 = (deg[u] == i) ? p2[u >> 1][u & 1] : g0;
            g0 = fmaxf(g0, 0.f);

            // (d) incremental W3 accumulation (scalar v_fmac, SGPR h operand)
            #pragma unroll
            for (int t = 0; t < 8; ++t) {
                const int k = base + 63 * t;
                const float wa = w3s[t * 128 + lane];        // W3[k, lane]
                const float wb = w3s[t * 128 + 64 + lane];   // W3[k, 64+lane]
                const float h0 = bcast(g0, k >> 3);
                acc[0] = fmaf(h0, wa, acc[0]);
                acc[1] = fmaf(h0, wb, acc[1]);
            }
            if (h9) {
                const float wa = w3s[8 * 128 + lane];
                const float wb = w3s[8 * 128 + 64 + lane];
                const float h0 = bcast(g0, 63);
                acc[0] = fmaf(h0, wa, acc[0]);
                acc[1] = fmaf(h0, wb, acc[1]);
            }
        }

        // (e) z_i: column i's totals live in lane i; every lane computes its
        // own candidate (parallel), one readlane extracts; feed back into p1.
        {
            const float am = acc[0] + b3m;
            const float ap = acc[1] + b3p;
            const float sp = fast_softplus(ap);
            const float zc = fmaf(sp, ep, am);
            if (lane == i) z = bcast(zc, i);
            const u64 zp = rl_pair(zc, i);
            #pragma unroll
            for (int j = 0; j < 4; ++j) p1[j] = pk_fma_s(zp, w1v[j], p1[j]);
        }

        __syncthreads();
    }

    out[rrow * DD + lane] = z;
}

extern "C" void kernel_launch(void* const* d_in, const int* in_sizes, int n_in,
                              void* d_out, int out_size, void* d_ws, size_t ws_size,
                              hipStream_t stream) {
    const float* ctx = (const float*)d_in[0];
    const float* eps = (const float*)d_in[1];
    const float* W1  = (const float*)d_in[2];
    const float* b1  = (const float*)d_in[3];
    const float* W2  = (const float*)d_in[4];
    const float* b2  = (const float*)d_in[5];
    const float* W3  = (const float*)d_in[6];
    const float* b3  = (const float*)d_in[7];
    (void)d_ws; (void)ws_size; (void)in_sizes; (void)n_in; (void)out_size;

    made_sample<<<BATCH / 8, 512, 0, stream>>>(ctx, eps, W1, b1, W2, b2, W3, b3,
                                               (float*)d_out);
}